// Round 4
// baseline (898.800 us; speedup 1.0000x reference)
//
#include <hip/hip_runtime.h>
#include <hip/hip_bf16.h>
#include <math.h>

#define H 128
#define XS 300
#define NCLS 5
#define KPAD 320
#define G 8    // parents per block in level kernel
#define NXCD 8

typedef __attribute__((ext_vector_type(8))) short short8;
typedef __attribute__((ext_vector_type(4))) float f32x4;

static __device__ inline unsigned short f2bf(float f) {
    __hip_bfloat16 h = __float2bfloat16(f);
    return *reinterpret_cast<unsigned short*>(&h);
}

// ---------------------------------------------------------------------------
// mask conversion with dtype auto-detect (bool-bytes vs int32)
// ---------------------------------------------------------------------------
__global__ void mask_conv_kernel(const void* __restrict__ mask_raw,
                                 float* __restrict__ m, int n) {
    const unsigned int* w = (const unsigned int*)mask_raw;
    bool is_bytes = false;
#pragma unroll
    for (int i = 0; i < 16; i++) is_bytes |= (w[i] > 1u);
    int idx = blockIdx.x * blockDim.x + threadIdx.x;
    if (idx >= n) return;
    float mv;
    if (is_bytes) mv = ((const unsigned char*)mask_raw)[idx] ? 1.f : 0.f;
    else          mv = ((const int*)mask_raw)[idx] ? 1.f : 0.f;
    m[idx] = mv;
}

// ---------------------------------------------------------------------------
// W -> transposed bf16: Wb_t[c][k], c in [0,512) (384 iou cols then 128 f),
// k in [0,320) zero-padded past 300
// ---------------------------------------------------------------------------
__global__ void wconv_kernel(const float* __restrict__ W_iou,
                             const float* __restrict__ W_f,
                             unsigned short* __restrict__ Wb_t) {
    int c = blockIdx.x;     // 0..511
    int k = threadIdx.x;    // 0..319
    float v = 0.f;
    if (k < XS) v = (c < 384) ? W_iou[(size_t)k * 384 + c]
                              : W_f[(size_t)k * 128 + (c - 384)];
    Wb_t[(size_t)c * KPAD + k] = f2bf(v);
}

// ---------------------------------------------------------------------------
// Phase A via MFMA: C[n x 512] = x[n x 300] @ [W_iou | W_f], bias+mask fused.
// Flat grid, XCD-chunked swizzle (bijective, m204 form): the 4 col-tiles of
// each 128-row band run on the SAME XCD -> x fetched once per band.
// ---------------------------------------------------------------------------
__global__ __launch_bounds__(256) void gemm_in_mfma(
    const float* __restrict__ x, const float* __restrict__ m,
    const unsigned short* __restrict__ Wb_t,
    const float* __restrict__ b_iou, const float* __restrict__ b_f,
    float* __restrict__ iou_in, float* __restrict__ f_in, int n)
{
    __shared__ __align__(16) unsigned short Asld[128][72];
    __shared__ __align__(16) unsigned short Bsld[128][72];

    // XCD-chunked bijective swizzle
    int bid = blockIdx.x;
    int nwg = gridDim.x;
    int q = nwg / NXCD, r = nwg % NXCD;
    int xcd = bid % NXCD, slot = bid / NXCD;
    int nid = (xcd < r) ? (xcd * (q + 1) + slot)
                        : (r * (q + 1) + (xcd - r) * q + slot);
    int bn = nid & 3;          // col tile 0..3
    int bm = nid >> 2;         // row band

    int t    = threadIdx.x;
    int lane = t & 63;
    int wid  = t >> 6;
    int wr = wid >> 1, wc = wid & 1;

    int r0 = bm * 128;
    int c0 = bn * 128;

    f32x4 acc[4][4];
#pragma unroll
    for (int i = 0; i < 4; i++)
#pragma unroll
        for (int j = 0; j < 4; j++) acc[i][j] = (f32x4)0.f;

    for (int k0 = 0; k0 < KPAD; k0 += 64) {
        // --- stage A: 128 rows x 64 k
        {
            int rr = t >> 4;
            int kq = (t & 15) << 2;
            int kg = k0 + kq;
#pragma unroll
            for (int p = 0; p < 8; p++) {
                int row  = r0 + rr + p * 16;
                int rowc = row < n ? row : n - 1;
                float4 v;
                if (kg + 4 <= XS) v = *(const float4*)&x[(size_t)rowc * XS + kg];
                else              v = make_float4(0.f, 0.f, 0.f, 0.f);
                ushort4 b4;
                b4.x = f2bf(v.x); b4.y = f2bf(v.y);
                b4.z = f2bf(v.z); b4.w = f2bf(v.w);
                *(ushort4*)&Asld[rr + p * 16][kq] = b4;
            }
        }
        // --- stage B: 128 cols x 64 k from Wb_t
        {
            int rr  = t >> 3;
            int kq8 = (t & 7) << 3;
#pragma unroll
            for (int p = 0; p < 4; p++) {
                int col = c0 + rr + p * 32;
                uint4 v = *(const uint4*)&Wb_t[(size_t)col * KPAD + k0 + kq8];
                *(uint4*)&Bsld[rr + p * 32][kq8] = v;
            }
        }
        __syncthreads();

#pragma unroll
        for (int ks = 0; ks < 2; ks++) {
            int kc = ks * 32 + (lane >> 4) * 8;
            short8 af[4], bf[4];
#pragma unroll
            for (int mi = 0; mi < 4; mi++)
                af[mi] = *(const short8*)&Asld[wr * 64 + mi * 16 + (lane & 15)][kc];
#pragma unroll
            for (int ni = 0; ni < 4; ni++)
                bf[ni] = *(const short8*)&Bsld[wc * 64 + ni * 16 + (lane & 15)][kc];
#pragma unroll
            for (int mi = 0; mi < 4; mi++)
#pragma unroll
                for (int ni = 0; ni < 4; ni++)
                    acc[mi][ni] = __builtin_amdgcn_mfma_f32_16x16x32_bf16(
                        af[mi], bf[ni], acc[mi][ni], 0, 0, 0);
        }
        __syncthreads();
    }

    // --- epilogue: bias + mask
    const float* bias;
    float* outp;
    int ldw, colbase;
    if (bn < 3) { bias = b_iou; outp = iou_in; ldw = 384; colbase = bn * 128; }
    else        { bias = b_f;   outp = f_in;   ldw = 128; colbase = 0; }

    float bias_v[4];
#pragma unroll
    for (int ni = 0; ni < 4; ni++)
        bias_v[ni] = bias[colbase + wc * 64 + ni * 16 + (lane & 15)];

#pragma unroll
    for (int mi = 0; mi < 4; mi++) {
#pragma unroll
        for (int j = 0; j < 4; j++) {
            int row = r0 + wr * 64 + mi * 16 + (lane >> 4) * 4 + j;
            if (row >= n) continue;
            float mv = m[row];
#pragma unroll
            for (int ni = 0; ni < 4; ni++) {
                int col = colbase + wc * 64 + ni * 16 + (lane & 15);
                outp[(size_t)row * ldw + col] = mv * (acc[mi][ni][j] + bias_v[ni]);
            }
        }
    }
}

// ---------------------------------------------------------------------------
// Leaves (level 10): c = i*u, h = o*tanh(c); float4 vectorized
// ---------------------------------------------------------------------------
__global__ void leaf_kernel(const float* __restrict__ iou_in,
                            float* __restrict__ h, float* __restrict__ c,
                            int start, int count)
{
    int idx = blockIdx.x * blockDim.x + threadIdx.x;
    int total = count * 32;
    if (idx >= total) return;
    int v = start + (idx >> 5);
    int d = (idx & 31) * 4;
    const float* row = iou_in + (size_t)v * 384;
    float4 iv = *(const float4*)&row[d];
    float4 ov = *(const float4*)&row[128 + d];
    float4 uv = *(const float4*)&row[256 + d];
    float4 cv, hv;
    {
        float ig, og, ug;
        ig = 1.f / (1.f + __expf(-iv.x)); og = 1.f / (1.f + __expf(-ov.x)); ug = tanhf(uv.x);
        cv.x = ig * ug; hv.x = og * tanhf(cv.x);
        ig = 1.f / (1.f + __expf(-iv.y)); og = 1.f / (1.f + __expf(-ov.y)); ug = tanhf(uv.y);
        cv.y = ig * ug; hv.y = og * tanhf(cv.y);
        ig = 1.f / (1.f + __expf(-iv.z)); og = 1.f / (1.f + __expf(-ov.z)); ug = tanhf(uv.z);
        cv.z = ig * ug; hv.z = og * tanhf(cv.z);
        ig = 1.f / (1.f + __expf(-iv.w)); og = 1.f / (1.f + __expf(-ov.w)); ug = tanhf(uv.w);
        cv.w = ig * ug; hv.w = og * tanhf(cv.w);
    }
    *(float4*)&c[(size_t)v * H + d] = cv;
    *(float4*)&h[(size_t)v * H + d] = hv;
}

// ---------------------------------------------------------------------------
// One internal level: G=8 parents per block (amortizes U_iou/U_f reads)
// ---------------------------------------------------------------------------
__global__ __launch_bounds__(128) void level_kernel(
    const float* __restrict__ iou_in, const float* __restrict__ f_in,
    const float* __restrict__ U_iou, const float* __restrict__ U_f,
    float* __restrict__ h, float* __restrict__ c,
    int P0, int NP)
{
    __shared__ float ch_h[3 * G][H];
    __shared__ float hs[G][H];

    int d  = threadIdx.x;
    int p0 = blockIdx.x * G;
    int C0 = 3 * P0 + 1;

    int nch = 3 * (NP - p0);
    if (nch > 3 * G) nch = 3 * G;

#pragma unroll
    for (int cc = 0; cc < 3 * G; cc++) {
        int child = C0 + 3 * p0 + cc;
        ch_h[cc][d] = (cc < nch) ? h[(size_t)child * H + d] : 0.f;
    }
    __syncthreads();

    float acc[3 * G];
#pragma unroll
    for (int cc = 0; cc < 3 * G; cc++) acc[cc] = 0.f;
    for (int k = 0; k < H; k += 4) {
        float u0 = U_f[(size_t)(k + 0) * H + d];
        float u1 = U_f[(size_t)(k + 1) * H + d];
        float u2 = U_f[(size_t)(k + 2) * H + d];
        float u3 = U_f[(size_t)(k + 3) * H + d];
#pragma unroll
        for (int cc = 0; cc < 3 * G; cc++) {
            float4 hv = *reinterpret_cast<const float4*>(&ch_h[cc][k]);
            acc[cc] = fmaf(hv.x, u0, acc[cc]);
            acc[cc] = fmaf(hv.y, u1, acc[cc]);
            acc[cc] = fmaf(hv.z, u2, acc[cc]);
            acc[cc] = fmaf(hv.w, u3, acc[cc]);
        }
    }

    float fcs[G];
#pragma unroll
    for (int g = 0; g < G; g++) {
        int p = p0 + g;
        bool valid = (p < NP);
        float fpre = valid ? f_in[(size_t)(P0 + p) * H + d] : 0.f;
        float s = 0.f, hsum = 0.f;
#pragma unroll
        for (int j = 0; j < 3; j++) {
            int cc = 3 * g + j;
            float fg = 1.f / (1.f + __expf(-(fpre + acc[cc])));
            float cvv = valid ? c[(size_t)(C0 + 3 * p + j) * H + d] : 0.f;
            s    += fg * cvv;
            hsum += ch_h[cc][d];
        }
        fcs[g]   = s;
        hs[g][d] = hsum;
    }
    __syncthreads();

    float a0[G], a1[G], a2[G];
#pragma unroll
    for (int g = 0; g < G; g++) { a0[g] = 0.f; a1[g] = 0.f; a2[g] = 0.f; }
#pragma unroll 2
    for (int k = 0; k < H; k++) {
        float u0 = U_iou[(size_t)k * 384 + d];
        float u1 = U_iou[(size_t)k * 384 + 128 + d];
        float u2 = U_iou[(size_t)k * 384 + 256 + d];
#pragma unroll
        for (int g = 0; g < G; g++) {
            float hv = hs[g][k];
            a0[g] = fmaf(hv, u0, a0[g]);
            a1[g] = fmaf(hv, u1, a1[g]);
            a2[g] = fmaf(hv, u2, a2[g]);
        }
    }

#pragma unroll
    for (int g = 0; g < G; g++) {
        int p = p0 + g;
        if (p >= NP) continue;
        int v = P0 + p;
        const float* irow = iou_in + (size_t)v * 384;
        float ig = 1.f / (1.f + __expf(-(irow[d]       + a0[g])));
        float og = 1.f / (1.f + __expf(-(irow[128 + d] + a1[g])));
        float ug = tanhf(irow[256 + d] + a2[g]);
        float cv = ig * ug + fcs[g];
        float hv = og * tanhf(cv);
        c[(size_t)v * H + d] = cv;
        h[(size_t)v * H + d] = hv;
    }
}

// ---------------------------------------------------------------------------
// Output head: out = h @ W_out + b_out (n x 5)
// ---------------------------------------------------------------------------
__global__ __launch_bounds__(256) void out_kernel(
    const float* __restrict__ h, const float* __restrict__ W_out,
    const float* __restrict__ b_out, float* __restrict__ out, int n)
{
    int wave = (blockIdx.x * blockDim.x + threadIdx.x) >> 6;
    int lane = threadIdx.x & 63;
    if (wave >= n) return;
    const float* hr = h + (size_t)wave * H;
    float h0 = hr[lane], h1 = hr[lane + 64];
    float a[NCLS];
#pragma unroll
    for (int j = 0; j < NCLS; j++)
        a[j] = h0 * W_out[lane * NCLS + j] + h1 * W_out[(lane + 64) * NCLS + j];
#pragma unroll
    for (int off = 32; off > 0; off >>= 1)
#pragma unroll
        for (int j = 0; j < NCLS; j++)
            a[j] += __shfl_down(a[j], off, 64);
    if (lane == 0) {
#pragma unroll
        for (int j = 0; j < NCLS; j++)
            out[(size_t)wave * NCLS + j] = a[j] + b_out[j];
    }
}

// ---------------------------------------------------------------------------
extern "C" void kernel_launch(void* const* d_in, const int* in_sizes, int n_in,
                              void* d_out, int out_size, void* d_ws, size_t ws_size,
                              hipStream_t stream) {
    const float* x     = (const float*)d_in[0];
    const void*  mask  = d_in[1];
    const float* W_iou = (const float*)d_in[2];
    const float* b_iou = (const float*)d_in[3];
    const float* W_f   = (const float*)d_in[4];
    const float* b_f   = (const float*)d_in[5];
    const float* U_iou = (const float*)d_in[6];
    const float* U_f   = (const float*)d_in[7];
    const float* W_out = (const float*)d_in[8];
    const float* b_out = (const float*)d_in[9];
    float* out = (float*)d_out;

    int n = in_sizes[1];   // 88573

    float* ws     = (float*)d_ws;
    float* iou_in = ws;                              // n*384
    float* f_in   = iou_in + (size_t)n * 384;        // n*128
    float* hbuf   = f_in   + (size_t)n * 128;        // n*128
    float* cbuf   = hbuf   + (size_t)n * 128;        // n*128
    float* mbuf   = cbuf   + (size_t)n * 128;        // n
    unsigned short* Wb_t = (unsigned short*)(mbuf + n);  // 512*320 bf16

    int pow3[11];
    pow3[0] = 1;
    for (int i = 1; i < 11; i++) pow3[i] = pow3[i - 1] * 3;

    // 0. mask -> float ; W -> bf16 transposed
    mask_conv_kernel<<<(n + 255) / 256, 256, 0, stream>>>(mask, mbuf, n);
    wconv_kernel<<<512, KPAD, 0, stream>>>(W_iou, W_f, Wb_t);

    // 1. input GEMM (MFMA bf16, fused bias + mask), XCD-swizzled flat grid
    {
        int nwg = 4 * ((n + 127) / 128);
        gemm_in_mfma<<<nwg, 256, 0, stream>>>(x, mbuf, Wb_t, b_iou, b_f,
                                              iou_in, f_in, n);
    }

    // 2. leaves (level 10)
    {
        int start = (pow3[10] - 1) / 2;   // 29524
        int count = pow3[10];             // 59049
        int total = count * 32;
        leaf_kernel<<<(total + 255) / 256, 256, 0, stream>>>(iou_in, hbuf, cbuf,
                                                             start, count);
    }

    // 3. internal levels 9..0
    for (int lvl = 9; lvl >= 0; --lvl) {
        int NP = pow3[lvl];
        int P0 = (pow3[lvl] - 1) / 2;
        int grid = (NP + G - 1) / G;
        level_kernel<<<grid, 128, 0, stream>>>(iou_in, f_in, U_iou, U_f,
                                               hbuf, cbuf, P0, NP);
    }

    // 4. output head
    {
        int blocks = (n + 3) / 4;
        out_kernel<<<blocks, 256, 0, stream>>>(hbuf, W_out, b_out, out, n);
    }
}

// Round 5
// 793.205 us; speedup vs baseline: 1.1331x; 1.1331x over previous
//
#include <hip/hip_runtime.h>
#include <hip/hip_bf16.h>
#include <math.h>

#define H 128
#define XS 300
#define NCLS 5
#define KPAD 320
#define NXCD 8

typedef __attribute__((ext_vector_type(8))) short short8;
typedef __attribute__((ext_vector_type(4))) float f32x4;

static __device__ inline unsigned short f2bf(float f) {
    __hip_bfloat16 h = __float2bfloat16(f);
    return *reinterpret_cast<unsigned short*>(&h);
}
static __device__ inline float bf2f(unsigned short u) {
    unsigned int x = ((unsigned int)u) << 16;
    return __builtin_bit_cast(float, x);
}
static __device__ inline float sigm(float v) { return 1.f / (1.f + __expf(-v)); }

// ---------------------------------------------------------------------------
// mask conversion with dtype auto-detect (bool-bytes vs int32)
// ---------------------------------------------------------------------------
__global__ void mask_conv_kernel(const void* __restrict__ mask_raw,
                                 float* __restrict__ m, int n) {
    const unsigned int* w = (const unsigned int*)mask_raw;
    bool is_bytes = false;
#pragma unroll
    for (int i = 0; i < 16; i++) is_bytes |= (w[i] > 1u);
    int idx = blockIdx.x * blockDim.x + threadIdx.x;
    if (idx >= n) return;
    float mv;
    if (is_bytes) mv = ((const unsigned char*)mask_raw)[idx] ? 1.f : 0.f;
    else          mv = ((const int*)mask_raw)[idx] ? 1.f : 0.f;
    m[idx] = mv;
}

// ---------------------------------------------------------------------------
// W -> transposed bf16 (single precision path for input GEMM)
// ---------------------------------------------------------------------------
__global__ void wconv_kernel(const float* __restrict__ W_iou,
                             const float* __restrict__ W_f,
                             unsigned short* __restrict__ Wb_t) {
    int c = blockIdx.x;     // 0..511
    int k = threadIdx.x;    // 0..319
    float v = 0.f;
    if (k < XS) v = (c < 384) ? W_iou[(size_t)k * 384 + c]
                              : W_f[(size_t)k * 128 + (c - 384)];
    Wb_t[(size_t)c * KPAD + k] = f2bf(v);
}

// ---------------------------------------------------------------------------
// U_f / U_iou -> transposed split-bf16 (hi, lo): Ut[col][k], k in [0,128)
// ---------------------------------------------------------------------------
__global__ void uconv_kernel(const float* __restrict__ U_f,
                             const float* __restrict__ U_iou,
                             unsigned short* __restrict__ Uf_hi,
                             unsigned short* __restrict__ Uf_lo,
                             unsigned short* __restrict__ Uiou_hi,
                             unsigned short* __restrict__ Uiou_lo) {
    int c = blockIdx.x;     // 0..511: 0..127 -> U_f col, 128.. -> U_iou col
    int k = threadIdx.x;    // 0..127
    if (c < 128) {
        float v = U_f[(size_t)k * 128 + c];
        unsigned short hi = f2bf(v);
        Uf_hi[(size_t)c * 128 + k] = hi;
        Uf_lo[(size_t)c * 128 + k] = f2bf(v - bf2f(hi));
    } else {
        int cc = c - 128;
        float v = U_iou[(size_t)k * 384 + cc];
        unsigned short hi = f2bf(v);
        Uiou_hi[(size_t)cc * 128 + k] = hi;
        Uiou_lo[(size_t)cc * 128 + k] = f2bf(v - bf2f(hi));
    }
}

// ---------------------------------------------------------------------------
// Phase A via MFMA (unchanged from round 3/4, XCD-swizzled)
// ---------------------------------------------------------------------------
__global__ __launch_bounds__(256) void gemm_in_mfma(
    const float* __restrict__ x, const float* __restrict__ m,
    const unsigned short* __restrict__ Wb_t,
    const float* __restrict__ b_iou, const float* __restrict__ b_f,
    float* __restrict__ iou_in, float* __restrict__ f_in, int n)
{
    __shared__ __align__(16) unsigned short Asld[128][72];
    __shared__ __align__(16) unsigned short Bsld[128][72];

    int bid = blockIdx.x;
    int nwg = gridDim.x;
    int q = nwg / NXCD, r = nwg % NXCD;
    int xcd = bid % NXCD, slot = bid / NXCD;
    int nid = (xcd < r) ? (xcd * (q + 1) + slot)
                        : (r * (q + 1) + (xcd - r) * q + slot);
    int bn = nid & 3;
    int bm = nid >> 2;

    int t    = threadIdx.x;
    int lane = t & 63;
    int wid  = t >> 6;
    int wr = wid >> 1, wc = wid & 1;

    int r0 = bm * 128;
    int c0 = bn * 128;

    f32x4 acc[4][4];
#pragma unroll
    for (int i = 0; i < 4; i++)
#pragma unroll
        for (int j = 0; j < 4; j++) acc[i][j] = (f32x4)0.f;

    for (int k0 = 0; k0 < KPAD; k0 += 64) {
        {
            int rr = t >> 4;
            int kq = (t & 15) << 2;
            int kg = k0 + kq;
#pragma unroll
            for (int p = 0; p < 8; p++) {
                int row  = r0 + rr + p * 16;
                int rowc = row < n ? row : n - 1;
                float4 v;
                if (kg + 4 <= XS) v = *(const float4*)&x[(size_t)rowc * XS + kg];
                else              v = make_float4(0.f, 0.f, 0.f, 0.f);
                ushort4 b4;
                b4.x = f2bf(v.x); b4.y = f2bf(v.y);
                b4.z = f2bf(v.z); b4.w = f2bf(v.w);
                *(ushort4*)&Asld[rr + p * 16][kq] = b4;
            }
        }
        {
            int rr  = t >> 3;
            int kq8 = (t & 7) << 3;
#pragma unroll
            for (int p = 0; p < 4; p++) {
                int col = c0 + rr + p * 32;
                uint4 v = *(const uint4*)&Wb_t[(size_t)col * KPAD + k0 + kq8];
                *(uint4*)&Bsld[rr + p * 32][kq8] = v;
            }
        }
        __syncthreads();

#pragma unroll
        for (int ks = 0; ks < 2; ks++) {
            int kc = ks * 32 + (lane >> 4) * 8;
            short8 af[4], bf[4];
#pragma unroll
            for (int mi = 0; mi < 4; mi++)
                af[mi] = *(const short8*)&Asld[wr * 64 + mi * 16 + (lane & 15)][kc];
#pragma unroll
            for (int ni = 0; ni < 4; ni++)
                bf[ni] = *(const short8*)&Bsld[wc * 64 + ni * 16 + (lane & 15)][kc];
#pragma unroll
            for (int mi = 0; mi < 4; mi++)
#pragma unroll
                for (int ni = 0; ni < 4; ni++)
                    acc[mi][ni] = __builtin_amdgcn_mfma_f32_16x16x32_bf16(
                        af[mi], bf[ni], acc[mi][ni], 0, 0, 0);
        }
        __syncthreads();
    }

    const float* bias;
    float* outp;
    int ldw, colbase;
    if (bn < 3) { bias = b_iou; outp = iou_in; ldw = 384; colbase = bn * 128; }
    else        { bias = b_f;   outp = f_in;   ldw = 128; colbase = 0; }

    float bias_v[4];
#pragma unroll
    for (int ni = 0; ni < 4; ni++)
        bias_v[ni] = bias[colbase + wc * 64 + ni * 16 + (lane & 15)];

#pragma unroll
    for (int mi = 0; mi < 4; mi++) {
#pragma unroll
        for (int j = 0; j < 4; j++) {
            int row = r0 + wr * 64 + mi * 16 + (lane >> 4) * 4 + j;
            if (row >= n) continue;
            float mv = m[row];
#pragma unroll
            for (int ni = 0; ni < 4; ni++) {
                int col = colbase + wc * 64 + ni * 16 + (lane & 15);
                outp[(size_t)row * ldw + col] = mv * (acc[mi][ni][j] + bias_v[ni]);
            }
        }
    }
}

// ---------------------------------------------------------------------------
// Leaves: c = i*u (fp32), h -> split bf16 hi/lo
// ---------------------------------------------------------------------------
__global__ void leaf_kernel(const float* __restrict__ iou_in,
                            unsigned short* __restrict__ h_hi,
                            unsigned short* __restrict__ h_lo,
                            float* __restrict__ c,
                            int start, int count)
{
    int idx = blockIdx.x * blockDim.x + threadIdx.x;
    int total = count * 32;
    if (idx >= total) return;
    int v = start + (idx >> 5);
    int d = (idx & 31) * 4;
    const float* row = iou_in + (size_t)v * 384;
    float4 iv = *(const float4*)&row[d];
    float4 ov = *(const float4*)&row[128 + d];
    float4 uv = *(const float4*)&row[256 + d];
    float cv[4], hv[4];
    float ivv[4] = {iv.x, iv.y, iv.z, iv.w};
    float ovv[4] = {ov.x, ov.y, ov.z, ov.w};
    float uvv[4] = {uv.x, uv.y, uv.z, uv.w};
#pragma unroll
    for (int e = 0; e < 4; e++) {
        float ig = sigm(ivv[e]), og = sigm(ovv[e]), ug = tanhf(uvv[e]);
        cv[e] = ig * ug;
        hv[e] = og * tanhf(cv[e]);
    }
    *(float4*)&c[(size_t)v * H + d] = make_float4(cv[0], cv[1], cv[2], cv[3]);
    ushort4 hh, hl;
    unsigned short s;
    s = f2bf(hv[0]); hh.x = s; hl.x = f2bf(hv[0] - bf2f(s));
    s = f2bf(hv[1]); hh.y = s; hl.y = f2bf(hv[1] - bf2f(s));
    s = f2bf(hv[2]); hh.z = s; hl.z = f2bf(hv[2] - bf2f(s));
    s = f2bf(hv[3]); hh.w = s; hl.w = f2bf(hv[3] - bf2f(s));
    *(ushort4*)&h_hi[(size_t)v * H + d] = hh;
    *(ushort4*)&h_lo[(size_t)v * H + d] = hl;
}

// ---------------------------------------------------------------------------
// Level GEMM 1: S = h_ch @ U_f  (M3 = 3*NP rows x 128)
// epilogue: fc = sigmoid(S + f_in[parent]) * c_ch, stored into fbuf child rows
// split-bf16: acc += Ah@Bh + Ah@Bl + Al@Bh
// ---------------------------------------------------------------------------
__global__ __launch_bounds__(256) void level_gemm_f(
    const unsigned short* __restrict__ h_hi, const unsigned short* __restrict__ h_lo,
    const float* __restrict__ c, float* fbuf,
    const unsigned short* __restrict__ Uf_hi, const unsigned short* __restrict__ Uf_lo,
    int P0, int NP)
{
    __shared__ __align__(16) unsigned short Ah[64][136];
    __shared__ __align__(16) unsigned short Al[64][136];

    int C0 = 3 * P0 + 1;
    int M3 = 3 * NP;
    int r0 = blockIdx.x * 64;
    int t = threadIdx.x;

    {   // stage A from h_hi/h_lo (already split)
        int tr = t >> 2;
        int tk = (t & 3) * 32;
        bool vr = (r0 + tr) < M3;
        size_t gb = (size_t)(C0 + r0 + tr) * H + tk;
        uint4 z = {0, 0, 0, 0};
#pragma unroll
        for (int kk = 0; kk < 4; kk++) {
            uint4 vh = vr ? *(const uint4*)&h_hi[gb + kk * 8] : z;
            uint4 vl = vr ? *(const uint4*)&h_lo[gb + kk * 8] : z;
            *(uint4*)&Ah[tr][tk + kk * 8] = vh;
            *(uint4*)&Al[tr][tk + kk * 8] = vl;
        }
    }
    __syncthreads();

    int lane = t & 63;
    int wid  = t >> 6;
    int nb = wid * 32;

    f32x4 acc[4][2];
#pragma unroll
    for (int mi = 0; mi < 4; mi++)
#pragma unroll
        for (int nf = 0; nf < 2; nf++) acc[mi][nf] = (f32x4)0.f;

#pragma unroll
    for (int ks = 0; ks < 4; ks++) {
        int kb = ks * 32 + (lane >> 4) * 8;
        short8 ah[4], al[4], bh[2], bl[2];
#pragma unroll
        for (int mi = 0; mi < 4; mi++) {
            ah[mi] = *(const short8*)&Ah[mi * 16 + (lane & 15)][kb];
            al[mi] = *(const short8*)&Al[mi * 16 + (lane & 15)][kb];
        }
#pragma unroll
        for (int nf = 0; nf < 2; nf++) {
            int bc = nb + nf * 16 + (lane & 15);
            bh[nf] = *(const short8*)&Uf_hi[(size_t)bc * 128 + kb];
            bl[nf] = *(const short8*)&Uf_lo[(size_t)bc * 128 + kb];
        }
#pragma unroll
        for (int mi = 0; mi < 4; mi++)
#pragma unroll
            for (int nf = 0; nf < 2; nf++) {
                acc[mi][nf] = __builtin_amdgcn_mfma_f32_16x16x32_bf16(ah[mi], bh[nf], acc[mi][nf], 0, 0, 0);
                acc[mi][nf] = __builtin_amdgcn_mfma_f32_16x16x32_bf16(ah[mi], bl[nf], acc[mi][nf], 0, 0, 0);
                acc[mi][nf] = __builtin_amdgcn_mfma_f32_16x16x32_bf16(al[mi], bh[nf], acc[mi][nf], 0, 0, 0);
            }
    }

#pragma unroll
    for (int mi = 0; mi < 4; mi++)
#pragma unroll
        for (int j = 0; j < 4; j++) {
            int rl = r0 + mi * 16 + (lane >> 4) * 4 + j;
            if (rl >= M3) continue;
            int gc = C0 + rl;
            int gp = P0 + rl / 3;
#pragma unroll
            for (int nf = 0; nf < 2; nf++) {
                int col = nb + nf * 16 + (lane & 15);
                float s = acc[mi][nf][j] + fbuf[(size_t)gp * H + col];
                fbuf[(size_t)gc * H + col] = sigm(s) * c[(size_t)gc * H + col];
            }
        }
}

// ---------------------------------------------------------------------------
// Level GEMM 2: T = hs @ U_iou (NP x 384), hs = sum of 3 children h
// (segment-sum fused into A-stage). Wave owns d-chunks on ALL 3 col planes
// -> i/o/u lane-local -> fully fused gate epilogue.
// ---------------------------------------------------------------------------
__global__ __launch_bounds__(256) void level_gemm_iou(
    const float* __restrict__ iou_in, float* fbuf,
    const unsigned short* __restrict__ Uiou_hi, const unsigned short* __restrict__ Uiou_lo,
    unsigned short* h_hi, unsigned short* h_lo, float* c,
    int P0, int NP)
{
    __shared__ __align__(16) unsigned short Ah[64][136];
    __shared__ __align__(16) unsigned short Al[64][136];

    int C0 = 3 * P0 + 1;
    int r0 = blockIdx.x * 64;
    int t = threadIdx.x;

    {   // stage A = segsum of 3 children (hi+lo -> fp32 -> re-split)
        int tr = t >> 2;
        int tk = (t & 3) * 32;
        int p = r0 + tr;
        bool vr = p < NP;
#pragma unroll
        for (int kk = 0; kk < 4; kk++) {
            int k8 = tk + kk * 8;
            float hs[8];
#pragma unroll
            for (int e = 0; e < 8; e++) hs[e] = 0.f;
            if (vr) {
#pragma unroll
                for (int j = 0; j < 3; j++) {
                    size_t cb = (size_t)(C0 + 3 * p + j) * H + k8;
                    short8 hh = *(const short8*)&h_hi[cb];
                    short8 hl = *(const short8*)&h_lo[cb];
#pragma unroll
                    for (int e = 0; e < 8; e++)
                        hs[e] += bf2f((unsigned short)hh[e]) + bf2f((unsigned short)hl[e]);
                }
            }
            short8 sh, sl;
#pragma unroll
            for (int e = 0; e < 8; e++) {
                unsigned short hi = f2bf(hs[e]);
                sh[e] = (short)hi;
                sl[e] = (short)f2bf(hs[e] - bf2f(hi));
            }
            *(short8*)&Ah[tr][k8] = sh;
            *(short8*)&Al[tr][k8] = sl;
        }
    }
    __syncthreads();

    int lane = t & 63;
    int wid  = t >> 6;
    int d0 = wid * 32;

    f32x4 acc[4][2][3];
#pragma unroll
    for (int mi = 0; mi < 4; mi++)
#pragma unroll
        for (int cn = 0; cn < 2; cn++)
#pragma unroll
            for (int pl = 0; pl < 3; pl++) acc[mi][cn][pl] = (f32x4)0.f;

#pragma unroll
    for (int ks = 0; ks < 4; ks++) {
        int kb = ks * 32 + (lane >> 4) * 8;
        short8 ah[4], al[4];
#pragma unroll
        for (int mi = 0; mi < 4; mi++) {
            ah[mi] = *(const short8*)&Ah[mi * 16 + (lane & 15)][kb];
            al[mi] = *(const short8*)&Al[mi * 16 + (lane & 15)][kb];
        }
        short8 bh[2][3], bl[2][3];
#pragma unroll
        for (int cn = 0; cn < 2; cn++)
#pragma unroll
            for (int pl = 0; pl < 3; pl++) {
                int bc = d0 + cn * 16 + pl * 128 + (lane & 15);
                bh[cn][pl] = *(const short8*)&Uiou_hi[(size_t)bc * 128 + kb];
                bl[cn][pl] = *(const short8*)&Uiou_lo[(size_t)bc * 128 + kb];
            }
#pragma unroll
        for (int mi = 0; mi < 4; mi++)
#pragma unroll
            for (int cn = 0; cn < 2; cn++)
#pragma unroll
                for (int pl = 0; pl < 3; pl++) {
                    acc[mi][cn][pl] = __builtin_amdgcn_mfma_f32_16x16x32_bf16(ah[mi], bh[cn][pl], acc[mi][cn][pl], 0, 0, 0);
                    acc[mi][cn][pl] = __builtin_amdgcn_mfma_f32_16x16x32_bf16(ah[mi], bl[cn][pl], acc[mi][cn][pl], 0, 0, 0);
                    acc[mi][cn][pl] = __builtin_amdgcn_mfma_f32_16x16x32_bf16(al[mi], bh[cn][pl], acc[mi][cn][pl], 0, 0, 0);
                }
    }

#pragma unroll
    for (int mi = 0; mi < 4; mi++)
#pragma unroll
        for (int j = 0; j < 4; j++) {
            int rl = r0 + mi * 16 + (lane >> 4) * 4 + j;
            if (rl >= NP) continue;
            int v = P0 + rl;
            int cb = C0 + 3 * rl;
#pragma unroll
            for (int cn = 0; cn < 2; cn++) {
                int col = d0 + cn * 16 + (lane & 15);
                size_t iob = (size_t)v * 384 + col;
                float iv = sigm(iou_in[iob]       + acc[mi][cn][0][j]);
                float ov = sigm(iou_in[iob + 128] + acc[mi][cn][1][j]);
                float uv = tanhf(iou_in[iob + 256] + acc[mi][cn][2][j]);
                float fcs = fbuf[(size_t)cb * H + col]
                          + fbuf[(size_t)(cb + 1) * H + col]
                          + fbuf[(size_t)(cb + 2) * H + col];
                float cv = iv * uv + fcs;
                float hv = ov * tanhf(cv);
                c[(size_t)v * H + col] = cv;
                unsigned short hi = f2bf(hv);
                h_hi[(size_t)v * H + col] = hi;
                h_lo[(size_t)v * H + col] = f2bf(hv - bf2f(hi));
            }
        }
}

// ---------------------------------------------------------------------------
// Output head: out = h @ W_out + b_out (n x 5); h = hi + lo
// ---------------------------------------------------------------------------
__global__ __launch_bounds__(256) void out_kernel(
    const unsigned short* __restrict__ h_hi, const unsigned short* __restrict__ h_lo,
    const float* __restrict__ W_out, const float* __restrict__ b_out,
    float* __restrict__ out, int n)
{
    int wave = (blockIdx.x * blockDim.x + threadIdx.x) >> 6;
    int lane = threadIdx.x & 63;
    if (wave >= n) return;
    size_t hb = (size_t)wave * H;
    float h0 = bf2f(h_hi[hb + lane]) + bf2f(h_lo[hb + lane]);
    float h1 = bf2f(h_hi[hb + lane + 64]) + bf2f(h_lo[hb + lane + 64]);
    float a[NCLS];
#pragma unroll
    for (int j = 0; j < NCLS; j++)
        a[j] = h0 * W_out[lane * NCLS + j] + h1 * W_out[(lane + 64) * NCLS + j];
#pragma unroll
    for (int off = 32; off > 0; off >>= 1)
#pragma unroll
        for (int j = 0; j < NCLS; j++)
            a[j] += __shfl_down(a[j], off, 64);
    if (lane == 0) {
#pragma unroll
        for (int j = 0; j < NCLS; j++)
            out[(size_t)wave * NCLS + j] = a[j] + b_out[j];
    }
}

// ---------------------------------------------------------------------------
extern "C" void kernel_launch(void* const* d_in, const int* in_sizes, int n_in,
                              void* d_out, int out_size, void* d_ws, size_t ws_size,
                              hipStream_t stream) {
    const float* x     = (const float*)d_in[0];
    const void*  mask  = d_in[1];
    const float* W_iou = (const float*)d_in[2];
    const float* b_iou = (const float*)d_in[3];
    const float* W_f   = (const float*)d_in[4];
    const float* b_f   = (const float*)d_in[5];
    const float* U_iou = (const float*)d_in[6];
    const float* U_f   = (const float*)d_in[7];
    const float* W_out = (const float*)d_in[8];
    const float* b_out = (const float*)d_in[9];
    float* out = (float*)d_out;

    int n = in_sizes[1];   // 88573
    size_t nn = (size_t)n;
    size_t mpad = (nn + 7) & ~(size_t)7;

    float* ws     = (float*)d_ws;
    float* iou_in = ws;                              // n*384 f32
    float* f_in   = iou_in + nn * 384;               // n*128 f32 (also fc buffer)
    float* cbuf   = f_in   + nn * 128;               // n*128 f32
    float* mbuf   = cbuf   + nn * 128;               // mpad f32
    unsigned short* h_hi = (unsigned short*)(mbuf + mpad);  // n*128 bf16
    unsigned short* h_lo = h_hi + nn * 128;                 // n*128 bf16
    unsigned short* Uf_hi   = h_lo + nn * 128;       // 128*128
    unsigned short* Uf_lo   = Uf_hi + 128 * 128;
    unsigned short* Uiou_hi = Uf_lo + 128 * 128;     // 384*128
    unsigned short* Uiou_lo = Uiou_hi + 384 * 128;
    // Wb_t aliases h_hi: consumed by gemm_in before any h is written
    unsigned short* Wb_t = h_hi;                     // 512*320

    int pow3[11];
    pow3[0] = 1;
    for (int i = 1; i < 11; i++) pow3[i] = pow3[i - 1] * 3;

    // 0. conversions
    mask_conv_kernel<<<(n + 255) / 256, 256, 0, stream>>>(mask, mbuf, n);
    wconv_kernel<<<512, KPAD, 0, stream>>>(W_iou, W_f, Wb_t);
    uconv_kernel<<<512, 128, 0, stream>>>(U_f, U_iou, Uf_hi, Uf_lo, Uiou_hi, Uiou_lo);

    // 1. input GEMM
    {
        int nwg = 4 * ((n + 127) / 128);
        gemm_in_mfma<<<nwg, 256, 0, stream>>>(x, mbuf, Wb_t, b_iou, b_f,
                                              iou_in, f_in, n);
    }

    // 2. leaves (level 10) — writes h_hi/h_lo (overwriting dead Wb_t region is fine
    //    only for leaf rows; Wb_t occupies h_hi rows [0..1280) which are internal
    //    rows written later by level kernels, after Wb_t is dead)
    {
        int start = (pow3[10] - 1) / 2;   // 29524
        int count = pow3[10];             // 59049
        int total = count * 32;
        leaf_kernel<<<(total + 255) / 256, 256, 0, stream>>>(iou_in, h_hi, h_lo,
                                                             cbuf, start, count);
    }

    // 3. internal levels 9..0 — two MFMA GEMMs per level
    for (int lvl = 9; lvl >= 0; --lvl) {
        int NP = pow3[lvl];
        int P0 = (pow3[lvl] - 1) / 2;
        int g1 = (3 * NP + 63) / 64;
        level_gemm_f<<<g1, 256, 0, stream>>>(h_hi, h_lo, cbuf, f_in,
                                             Uf_hi, Uf_lo, P0, NP);
        int g2 = (NP + 63) / 64;
        level_gemm_iou<<<g2, 256, 0, stream>>>(iou_in, f_in, Uiou_hi, Uiou_lo,
                                               h_hi, h_lo, cbuf, P0, NP);
    }

    // 4. output head
    {
        int blocks = (n + 3) / 4;
        out_kernel<<<blocks, 256, 0, stream>>>(h_hi, h_lo, W_out, b_out, out, n);
    }
}